// Round 4
// baseline (286.205 us; speedup 1.0000x reference)
//
#include <hip/hip_runtime.h>
#include <stdint.h>

#define N_PTS 4096
#define B_SZ 4
#define D_MODEL 256
#define K_NB 16
#define K1 17  // K+1 kept during selection; rank 0 (self) dropped

__device__ __forceinline__ uint64_t shfl_xor_u64(uint64_t v, int mask) {
    uint32_t lo = (uint32_t)v, hi = (uint32_t)(v >> 32);
    lo = (uint32_t)__shfl_xor((int)lo, mask, 64);
    hi = (uint32_t)__shfl_xor((int)hi, mask, 64);
    return ((uint64_t)hi << 32) | lo;
}

__device__ __forceinline__ uint64_t wave_min_u64(uint64_t m) {
#pragma unroll
    for (int o = 1; o < 64; o <<= 1) {
        const uint64_t t = shfl_xor_u64(m, o);
        m = (t < m) ? t : m;
    }
    return m;
}

// Monotone unsigned image of an IEEE f32 (total order, negatives first).
// Critical for the self-distance, which rounds to a tiny NEGATIVE for ~half
// the queries; raw-bit ordering would sort it LAST (R1's 2.35-absmax bug).
__device__ __forceinline__ uint32_t f32_mono(float f) {
    uint32_t u = __float_as_uint(f);
    return (u & 0x80000000u) ? ~u : (u | 0x80000000u);
}

__global__ __launch_bounds__(256) void knn_attn_kernel(
    const float* __restrict__ xyz, const float* __restrict__ feat,
    float* __restrict__ out)
{
    const int lane = threadIdx.x & 63;
    const int q = (int)((blockIdx.x * blockDim.x + threadIdx.x) >> 6);
    const int b = q >> 12;            // N_PTS = 4096
    const int n = q & (N_PTS - 1);

    const float* xb = xyz + (size_t)b * N_PTS * 3;

    // Replicate the numpy oracle's f32 arithmetic bit-exactly — NO FMA
    // anywhere (np.sum + np.einsum(optimize=False) are sequential,
    // separately-rounded f32 accumulations):
    //   sq  = fl(fl(x2 + y2) + z2), each square rounded
    //   dot = fl(fl(fl(x*x') + fl(y*y')) + fl(z*z'))
    //   d2  = fl( fl(sq_n + sq_c) - fl(2*dot) )
    const float xn = xb[3 * n + 0];
    const float yn = xb[3 * n + 1];
    const float zn = xb[3 * n + 2];
    const float sqn = __fadd_rn(__fadd_rn(__fmul_rn(xn, xn), __fmul_rn(yn, yn)),
                                __fmul_rn(zn, zn));

    // Per-lane sorted top-17 of keys (mono32(d2)<<32 | idx), ascending.
    // Tie-break for bit-equal d2: lower index first (matches stable top_k).
    uint64_t qk[K1];
#pragma unroll
    for (int i = 0; i < K1; ++i) qk[i] = ~0ull;

    // Wave-global reject bound: min over lanes of the lane-local 17th key.
    // Safe: if key > bound, the min-lane already holds 17 keys <= bound,
    // so key can never enter the global top-17. (Keys unique, no ==.)
    uint64_t bound = ~0ull;

    for (int s = 0; s < N_PTS / 64; ++s) {
        const int j = s * 64 + lane;
        const float cx = xb[3 * j + 0];
        const float cy = xb[3 * j + 1];
        const float cz = xb[3 * j + 2];
        const float sqc = __fadd_rn(
            __fadd_rn(__fmul_rn(cx, cx), __fmul_rn(cy, cy)), __fmul_rn(cz, cz));
        const float dt = __fadd_rn(
            __fadd_rn(__fmul_rn(cx, xn), __fmul_rn(cy, yn)), __fmul_rn(cz, zn));
        const float d2 = __fsub_rn(__fadd_rn(sqn, sqc), __fmul_rn(2.0f, dt));
        const uint64_t key = ((uint64_t)f32_mono(d2) << 32) | (uint32_t)j;

        if (key < bound) {
            // In-place sorted insert, descending slot order so qk[i-1] is
            // still the old value when slot i is computed.
#pragma unroll
            for (int i = K1 - 1; i >= 1; --i) {
                const bool ci   = qk[i] <= key;      // slot stays
                const bool cim1 = qk[i - 1] <= key;  // key lands here
                qk[i] = ci ? qk[i] : (cim1 ? key : qk[i - 1]);
            }
            qk[0] = (qk[0] <= key) ? qk[0] : key;
        }
        if ((s & 7) == 7) bound = wave_min_u64(qk[K1 - 1]);  // uniform cond
    }

    // Wave merge: 17 rounds of u64 wave-min over per-lane list heads.
    // Keys are unique (idx in low bits), so exactly one winner per round.
    int out_idx = 0;  // lane r-1 ends holding the rank-r neighbor index
    uint64_t head = qk[0];
#pragma unroll
    for (int r = 0; r < K1; ++r) {
        const uint64_t m = wave_min_u64(head);
        if (head == m) {  // unique winner pops its list
#pragma unroll
            for (int i = 0; i < K1 - 1; ++i) qk[i] = qk[i + 1];
            qk[K1 - 1] = ~0ull;
            head = qk[0];
        }
        if (r >= 1 && lane == (r - 1)) out_idx = (int)(m & 0xFFFFFFFFull);
    }

    // ---- Fused attention: lane owns dims [lane*4, lane*4+4) of D=256 ----
    const float* fb = feat + (size_t)b * N_PTS * D_MODEL;
    const float4 qf = *(const float4*)(fb + (size_t)n * D_MODEL + lane * 4);

    float4 vf[K_NB];
    float sc[K_NB];
#pragma unroll
    for (int k = 0; k < K_NB; ++k) {
        const int nbr = __shfl(out_idx, k, 64);
        vf[k] = *(const float4*)(fb + (size_t)nbr * D_MODEL + lane * 4);
        float p = qf.x * vf[k].x + qf.y * vf[k].y + qf.z * vf[k].z + qf.w * vf[k].w;
#pragma unroll
        for (int o = 1; o < 64; o <<= 1) p += __shfl_xor(p, o, 64);
        sc[k] = p * 0.0625f;  // SCALE = 1/sqrt(256)
    }

    float mx = sc[0];
#pragma unroll
    for (int k = 1; k < K_NB; ++k) mx = fmaxf(mx, sc[k]);
    float se = 0.0f;
#pragma unroll
    for (int k = 0; k < K_NB; ++k) {
        sc[k] = __expf(sc[k] - mx);
        se += sc[k];
    }
    const float inv = 1.0f / se;

    float4 acc = make_float4(0.f, 0.f, 0.f, 0.f);
#pragma unroll
    for (int k = 0; k < K_NB; ++k) {
        const float w = sc[k] * inv;
        acc.x += w * vf[k].x;
        acc.y += w * vf[k].y;
        acc.z += w * vf[k].z;
        acc.w += w * vf[k].w;
    }
    *(float4*)(out + (size_t)q * D_MODEL + lane * 4) = acc;
}

extern "C" void kernel_launch(void* const* d_in, const int* in_sizes, int n_in,
                              void* d_out, int out_size, void* d_ws, size_t ws_size,
                              hipStream_t stream) {
    const float* xyz  = (const float*)d_in[0];   // (4, 4096, 3) fp32
    const float* feat = (const float*)d_in[1];   // (4, 4096, 256) fp32
    float* out = (float*)d_out;                  // (4, 4096, 256) fp32

    const int n_queries = B_SZ * N_PTS;          // 16384, one wave each
    const int threads = 256;                     // 4 waves/block
    const int blocks = n_queries * 64 / threads; // 4096
    knn_attn_kernel<<<blocks, threads, 0, stream>>>(xyz, feat, out);
}

// Round 5
// 204.608 us; speedup vs baseline: 1.3988x; 1.3988x over previous
//
#include <hip/hip_runtime.h>
#include <stdint.h>

#define N_PTS 4096
#define B_SZ 4
#define D_MODEL 256
#define K_NB 16
#define K1 17  // K+1 kept; rank 0 (self) dropped

// Broadcast lane `srclane`'s u64 to all lanes (srclane wave-uniform).
__device__ __forceinline__ uint64_t bcast_u64(uint64_t v, int srclane) {
    const int sl = __builtin_amdgcn_readfirstlane(srclane);
    const uint32_t lo = (uint32_t)__builtin_amdgcn_readlane((int)(uint32_t)v, sl);
    const uint32_t hi = (uint32_t)__builtin_amdgcn_readlane((int)(v >> 32), sl);
    return ((uint64_t)hi << 32) | lo;
}

__device__ __forceinline__ uint64_t shfl_up1_u64(uint64_t v) {
    const uint32_t lo = (uint32_t)__shfl_up((int)(uint32_t)v, 1, 64);
    const uint32_t hi = (uint32_t)__shfl_up((int)(v >> 32), 1, 64);
    return ((uint64_t)hi << 32) | lo;
}

// Monotone unsigned image of an IEEE f32 (total order, negatives first).
// Self-distance can round to a tiny NEGATIVE; this keeps it at rank 0.
__device__ __forceinline__ uint32_t f32_mono(float f) {
    uint32_t u = __float_as_uint(f);
    return (u & 0x80000000u) ? ~u : (u | 0x80000000u);
}

__global__ __launch_bounds__(256) void knn_attn_kernel(
    const float* __restrict__ xyz, const float* __restrict__ feat,
    float* __restrict__ out)
{
    const int lane = threadIdx.x & 63;
    const int q = (int)((blockIdx.x * blockDim.x + threadIdx.x) >> 6);
    const int b = q >> 12;            // N_PTS = 4096
    const int n = q & (N_PTS - 1);

    const float* xb = xyz + (size_t)b * N_PTS * 3;

    // Oracle-exact f32 arithmetic (NO FMA anywhere) — same as passing R4:
    //   sq  = fl(fl(x2+y2)+z2); dot = fl(fl(fl(xx')+fl(yy'))+fl(zz'))
    //   d2  = fl( fl(sq_n+sq_c) - fl(2*dot) )
    const float xn = xb[3 * n + 0];
    const float yn = xb[3 * n + 1];
    const float zn = xb[3 * n + 2];
    const float sqn = __fadd_rn(__fadd_rn(__fmul_rn(xn, xn), __fmul_rn(yn, yn)),
                                __fmul_rn(zn, zn));

    // Wave-distributed sorted top-17: lane i (i<17) holds the rank-i key,
    // ascending; lanes 17..63 hold shifted-out garbage / sentinel.
    // Key = (mono32(d2) << 32) | idx  -> unique keys, stable idx tie-break.
    uint64_t held = ~0ull;
    uint64_t thr  = ~0ull;  // wave-uniform copy of held[16] (the 17th)

    for (int s = 0; s < N_PTS / 64; ++s) {
        const int j = s * 64 + lane;
        const float cx = xb[3 * j + 0];
        const float cy = xb[3 * j + 1];
        const float cz = xb[3 * j + 2];
        const float sqc = __fadd_rn(
            __fadd_rn(__fmul_rn(cx, cx), __fmul_rn(cy, cy)), __fmul_rn(cz, cz));
        const float dt = __fadd_rn(
            __fadd_rn(__fmul_rn(cx, xn), __fmul_rn(cy, yn)), __fmul_rn(cz, zn));
        const float d2 = __fsub_rn(__fadd_rn(sqn, sqc), __fmul_rn(2.0f, dt));
        const uint64_t key = ((uint64_t)f32_mono(d2) << 32) | (uint32_t)j;

        // Filter: only keys beating the current global 17th need insertion.
        uint64_t pass = __ballot(key < thr);
        while (pass) {
            const int L = (int)__ffsll((unsigned long long)pass) - 1;
            pass &= pass - 1;
            const uint64_t K = bcast_u64(key, L);
            if (K < thr) {  // re-check: thr may have tightened this chunk
                // O(1) sorted insert across lanes: lanes with held > K take
                // the neighbor's value (shift right); the boundary lane
                // (prev <= K < held) takes K.
                uint64_t prev = shfl_up1_u64(held);
                prev = (lane == 0) ? 0ull : prev;  // -inf below lane 0
                held = (held <= K) ? held : ((prev <= K) ? K : prev);
                thr = bcast_u64(held, 16);
            }
        }
    }

    // Lane r (r=1..16) now holds the rank-r neighbor's index.
    const int myidx = (int)(uint32_t)held;

    // ---- Fused attention: lane owns dims [lane*4, lane*4+4) of D=256 ----
    const float* fb = feat + (size_t)b * N_PTS * D_MODEL;
    const float4 qf = *(const float4*)(fb + (size_t)n * D_MODEL + lane * 4);

    float4 vf[K_NB];
    float sc[K_NB];
#pragma unroll
    for (int k = 0; k < K_NB; ++k) {
        const int nbr = __shfl(myidx, k + 1, 64);
        vf[k] = *(const float4*)(fb + (size_t)nbr * D_MODEL + lane * 4);
        float p = qf.x * vf[k].x + qf.y * vf[k].y + qf.z * vf[k].z + qf.w * vf[k].w;
#pragma unroll
        for (int o = 1; o < 64; o <<= 1) p += __shfl_xor(p, o, 64);
        sc[k] = p * 0.0625f;  // SCALE = 1/sqrt(256)
    }

    float mx = sc[0];
#pragma unroll
    for (int k = 1; k < K_NB; ++k) mx = fmaxf(mx, sc[k]);
    float se = 0.0f;
#pragma unroll
    for (int k = 0; k < K_NB; ++k) {
        sc[k] = __expf(sc[k] - mx);
        se += sc[k];
    }
    const float inv = 1.0f / se;

    float4 acc = make_float4(0.f, 0.f, 0.f, 0.f);
#pragma unroll
    for (int k = 0; k < K_NB; ++k) {
        const float w = sc[k] * inv;
        acc.x += w * vf[k].x;
        acc.y += w * vf[k].y;
        acc.z += w * vf[k].z;
        acc.w += w * vf[k].w;
    }
    *(float4*)(out + (size_t)q * D_MODEL + lane * 4) = acc;
}

extern "C" void kernel_launch(void* const* d_in, const int* in_sizes, int n_in,
                              void* d_out, int out_size, void* d_ws, size_t ws_size,
                              hipStream_t stream) {
    const float* xyz  = (const float*)d_in[0];   // (4, 4096, 3) fp32
    const float* feat = (const float*)d_in[1];   // (4, 4096, 256) fp32
    float* out = (float*)d_out;                  // (4, 4096, 256) fp32

    const int n_queries = B_SZ * N_PTS;          // 16384, one wave each
    const int threads = 256;                     // 4 waves/block
    const int blocks = n_queries * 64 / threads; // 4096
    knn_attn_kernel<<<blocks, threads, 0, stream>>>(xyz, feat, out);
}

// Round 6
// 176.288 us; speedup vs baseline: 1.6235x; 1.1607x over previous
//
#include <hip/hip_runtime.h>
#include <stdint.h>

#define N_PTS 4096
#define B_SZ 4
#define D_MODEL 256
#define K_NB 16

__device__ __forceinline__ uint64_t shfl_xor_u64(uint64_t v, int m) {
    const uint32_t lo = (uint32_t)__shfl_xor((int)(uint32_t)v, m, 64);
    const uint32_t hi = (uint32_t)__shfl_xor((int)(v >> 32), m, 64);
    return ((uint64_t)hi << 32) | lo;
}

__device__ __forceinline__ uint64_t shfl_up1_u64(uint64_t v) {
    const uint32_t lo = (uint32_t)__shfl_up((int)(uint32_t)v, 1, 64);
    const uint32_t hi = (uint32_t)__shfl_up((int)(v >> 32), 1, 64);
    return ((uint64_t)hi << 32) | lo;
}

// Monotone unsigned image of IEEE f32 bits (total order, negatives first).
// Self-distance can round to a tiny NEGATIVE; this keeps it at rank 0.
__device__ __forceinline__ uint32_t f32_mono(uint32_t u) {
    return (u & 0x80000000u) ? ~u : (u | 0x80000000u);
}
__device__ __forceinline__ float mono_to_f32(uint32_t m) {
    const uint32_t u = (m & 0x80000000u) ? (m ^ 0x80000000u) : ~m;
    return __uint_as_float(u);
}

__global__ __launch_bounds__(256) void knn_attn_kernel(
    const float* __restrict__ xyz, const float* __restrict__ feat,
    float* __restrict__ out)
{
    const int lane = threadIdx.x & 63;
    const int q = (int)((blockIdx.x * blockDim.x + threadIdx.x) >> 6);
    const int b = q >> 12;            // N_PTS = 4096
    const int n = q & (N_PTS - 1);

    const float* xb = xyz + (size_t)b * N_PTS * 3;

    // Oracle-exact f32 arithmetic (NO FMA anywhere) — matches passing R4/R5:
    //   sq  = fl(fl(x2+y2)+z2); dot = fl(fl(fl(xx')+fl(yy'))+fl(zz'))
    //   d2  = fl( fl(sq_n+sq_c) - fl(2*dot) )
    const float xn = xb[3 * n + 0];
    const float yn = xb[3 * n + 1];
    const float zn = xb[3 * n + 2];
    const float sqn = __fadd_rn(__fadd_rn(__fmul_rn(xn, xn), __fmul_rn(yn, yn)),
                                __fmul_rn(zn, zn));

    // Wave-distributed sorted list: after init, lane i holds the rank-i key
    // (ascending); only lanes 0..16 matter. Key = mono(d2)<<32 | idx
    // (unique keys; stable lower-idx tie-break, matching jax.lax.top_k).
    uint64_t held;

    // ---- Chunk 0: compute 64 keys, bitonic-sort across lanes (parallel
    // init — replaces 64 serial pops of the R5 scheme). ----
    {
        const float cx = xb[3 * lane + 0];
        const float cy = xb[3 * lane + 1];
        const float cz = xb[3 * lane + 2];
        const float sqc = __fadd_rn(
            __fadd_rn(__fmul_rn(cx, cx), __fmul_rn(cy, cy)), __fmul_rn(cz, cz));
        const float dt = __fadd_rn(
            __fadd_rn(__fmul_rn(cx, xn), __fmul_rn(cy, yn)), __fmul_rn(cz, zn));
        const float d2 = __fsub_rn(__fadd_rn(sqn, sqc), __fmul_rn(2.0f, dt));
        uint64_t key = ((uint64_t)f32_mono(__float_as_uint(d2)) << 32)
                       | (uint32_t)lane;
#pragma unroll
        for (int k = 2; k <= 64; k <<= 1) {
#pragma unroll
            for (int j2 = k >> 1; j2 > 0; j2 >>= 1) {
                const uint64_t o = shfl_xor_u64(key, j2);
                const bool keepMin =
                    (((lane & j2) == 0) == ((lane & k) == 0));
                const bool c = o < key;
                key = (c == keepMin) ? o : key;
            }
        }
        held = key;  // lane i = rank i of chunk 0
    }
    // Wave-uniform f32 threshold = d2 of the current 17th (lane 16).
    float thr_f = mono_to_f32(
        (uint32_t)__builtin_amdgcn_readlane((int)(held >> 32), 16));

    // ---- Chunks 1..63: filter by f32 threshold, serial O(1) inserts. ----
    for (int s = 1; s < N_PTS / 64; ++s) {
        const int j = s * 64 + lane;
        const float cx = xb[3 * j + 0];
        const float cy = xb[3 * j + 1];
        const float cz = xb[3 * j + 2];
        const float sqc = __fadd_rn(
            __fadd_rn(__fmul_rn(cx, cx), __fmul_rn(cy, cy)), __fmul_rn(cz, cz));
        const float dt = __fadd_rn(
            __fadd_rn(__fmul_rn(cx, xn), __fmul_rn(cy, yn)), __fmul_rn(cz, zn));
        const float d2 = __fsub_rn(__fadd_rn(sqn, sqc), __fmul_rn(2.0f, dt));

        // Stale-threshold filter (superset of needed inserts — safe: thr_f
        // is monotone non-increasing, and inserting a key worse than the
        // current lane-16 key provably leaves lanes 0..16 unchanged).
        uint64_t pass = __ballot(d2 <= thr_f);
        if (pass) {
            const uint32_t d2u = __float_as_uint(d2);
            do {
                const int L = (int)__ffsll((unsigned long long)pass) - 1;
                pass &= pass - 1;
                // Build insert key on the scalar pipe.
                const uint32_t ru =
                    (uint32_t)__builtin_amdgcn_readlane((int)d2u, L);
                const uint64_t K = ((uint64_t)f32_mono(ru) << 32)
                                   | (uint32_t)(s * 64 + L);
                // O(1) cross-lane sorted insert.
                uint64_t prev = shfl_up1_u64(held);
                prev = (lane == 0) ? 0ull : prev;  // -inf below lane 0
                held = (held <= K) ? held : ((prev <= K) ? K : prev);
            } while (pass);
            thr_f = mono_to_f32(
                (uint32_t)__builtin_amdgcn_readlane((int)(held >> 32), 16));
        }
    }

    // Lane r (r=1..16) holds the rank-r neighbor's index (rank 0 = self).
    const int myidx = (int)(uint32_t)held;

    // ---- Fused attention: lane owns dims [lane*4, lane*4+4) of D=256 ----
    const float* fb = feat + (size_t)b * N_PTS * D_MODEL;
    const float4 qf = *(const float4*)(fb + (size_t)n * D_MODEL + lane * 4);

    float4 vf[K_NB];
    float sc[K_NB];
#pragma unroll
    for (int k = 0; k < K_NB; ++k) {
        const int nbr = __shfl(myidx, k + 1, 64);
        vf[k] = *(const float4*)(fb + (size_t)nbr * D_MODEL + lane * 4);
        float p = qf.x * vf[k].x + qf.y * vf[k].y + qf.z * vf[k].z + qf.w * vf[k].w;
#pragma unroll
        for (int o = 1; o < 64; o <<= 1) p += __shfl_xor(p, o, 64);
        sc[k] = p * 0.0625f;  // SCALE = 1/sqrt(256)
    }

    float mx = sc[0];
#pragma unroll
    for (int k = 1; k < K_NB; ++k) mx = fmaxf(mx, sc[k]);
    float se = 0.0f;
#pragma unroll
    for (int k = 0; k < K_NB; ++k) {
        sc[k] = __expf(sc[k] - mx);
        se += sc[k];
    }
    const float inv = 1.0f / se;

    float4 acc = make_float4(0.f, 0.f, 0.f, 0.f);
#pragma unroll
    for (int k = 0; k < K_NB; ++k) {
        const float w = sc[k] * inv;
        acc.x += w * vf[k].x;
        acc.y += w * vf[k].y;
        acc.z += w * vf[k].z;
        acc.w += w * vf[k].w;
    }
    *(float4*)(out + (size_t)q * D_MODEL + lane * 4) = acc;
}

extern "C" void kernel_launch(void* const* d_in, const int* in_sizes, int n_in,
                              void* d_out, int out_size, void* d_ws, size_t ws_size,
                              hipStream_t stream) {
    const float* xyz  = (const float*)d_in[0];   // (4, 4096, 3) fp32
    const float* feat = (const float*)d_in[1];   // (4, 4096, 256) fp32
    float* out = (float*)d_out;                  // (4, 4096, 256) fp32

    const int n_queries = B_SZ * N_PTS;          // 16384, one wave each
    const int threads = 256;                     // 4 waves/block
    const int blocks = n_queries * 64 / threads; // 4096
    knn_attn_kernel<<<blocks, threads, 0, stream>>>(xyz, feat, out);
}